// Round 19
// baseline (100.356 us; speedup 1.0000x reference)
//
#include <hip/hip_runtime.h>

// AffineGPT2Attention: B=4, S=1024, D=1024, H=16, Dh=64
// R19: QKV rebuilt as m97-clone: BM=BN=128, BK=64, 4 waves, SINGLE-buffered
// 32KB LDS, plain __syncthreads, __launch_bounds__(256,8), grid 768 = exactly
// 3 blocks/CU resident. m97/m103 measured 874-912TF with THIS structure on
// THIS chip; its pipelining is CROSS-BLOCK (m114) — all 12 of my dbuf variants
// halved co-residency and starved that mechanism. Rest = R18-verbatim.

typedef __attribute__((ext_vector_type(4))) float  fx4;
typedef __attribute__((ext_vector_type(4))) short  sx4;
typedef __attribute__((ext_vector_type(8))) short  sx8;
typedef __attribute__((ext_vector_type(4))) float  f32x4;
typedef __attribute__((ext_vector_type(8))) __bf16 bf16x8;

#define DEVI static __device__ __forceinline__
#define BARRIER asm volatile("s_barrier" ::: "memory")
#define VMCNT0  asm volatile("s_waitcnt vmcnt(0)" ::: "memory")

DEVI short f2bf(float f) {  // f32 -> bf16 (RNE)
  unsigned u = __builtin_bit_cast(unsigned, f);
  u = (u + 0x7FFFu + ((u >> 16) & 1u)) >> 16;
  return (short)u;
}

DEVI fx4 mfma16(sx8 a, sx8 b, fx4 c) {
  return __builtin_amdgcn_mfma_f32_16x16x32_bf16(
      __builtin_bit_cast(bf16x8, a), __builtin_bit_cast(bf16x8, b), c, 0, 0, 0);
}

DEVI void gl_lds16(const void* g, void* l) {  // async global->LDS, 16B/lane
  __builtin_amdgcn_global_load_lds(
      (const __attribute__((address_space(1))) void*)g,
      (__attribute__((address_space(3))) void*)l, 16, 0, 0);
}

// ---------------- fused prologue: weight transposes + hs cast ---------------
__global__ __launch_bounds__(256) void prologue(
    const float* __restrict__ hs, short* __restrict__ hsb,
    const float* __restrict__ caw, short* __restrict__ wqkvt,
    const float* __restrict__ cpw, short* __restrict__ wprojt) {
  __shared__ float tbuf[32][33];
  const int bid = blockIdx.x, tid = threadIdx.x;
  if (bid < 4096) {
    const float* in;
    short* out;
    int C, bx, by;
    if (bid < 3072) {
      in = caw; out = wqkvt; C = 3072; bx = bid % 96; by = bid / 96;
    } else {
      int t = bid - 3072;
      in = cpw; out = wprojt; C = 1024; bx = t & 31; by = t >> 5;
    }
    const int R = 1024;
    int tx = tid & 31, ty = tid >> 5;
    int r0 = by * 32, c0 = bx * 32;
#pragma unroll
    for (int i = 0; i < 4; ++i)
      tbuf[ty + i * 8][tx] = in[(size_t)(r0 + ty + i * 8) * C + c0 + tx];
    __syncthreads();
#pragma unroll
    for (int i = 0; i < 4; ++i)
      out[(size_t)(c0 + ty + i * 8) * R + r0 + tx] = f2bf(tbuf[tx][ty + i * 8]);
  } else {
    int i = (bid - 4096) * 256 + tid;
    f32x4 v = *(const f32x4*)&hs[(size_t)i * 4];
    sx4 o;
#pragma unroll
    for (int j = 0; j < 4; ++j) o[j] = f2bf(v[j]);
    *(sx4*)&hsb[(size_t)i * 4] = o;
  }
}

// ---------------- QKV GEMM: m97-clone (single-buffer, high occupancy) -------
// C[4096][3072] = A[4096][1024] @ Bt[3072][1024]^T. BM=BN=128, BK=64.
// 256 thr = 4 waves (2x2), wave tile 64x64 = acc[4][4]; per K-step each wave:
// 8 gl_lds (stage) ; __syncthreads ; 8 ds_read_b128 + 16 MFMA ; __syncthreads.
// SINGLE 32KB LDS buffer -> with launch_bounds(256,8) and ~64 VGPR, 3 blocks
// co-resident per CU (grid 768 = exactly 3/CU, no tail). Latency hiding is
// cross-block (m114): while one block drains vmcnt at its barrier, the other
// two blocks' MFMAs issue. [*][64] 8-slot XOR swizzle (0-conflict, R8-R10).
// XCD map: x=bid&7 owns bn-triple [3x,3x+3) (768KB B slice, L2-resident).
__global__ __launch_bounds__(256, 8) void gemm_qkv(
    const short* __restrict__ A, const short* __restrict__ Bt,
    const float* __restrict__ bias, short* __restrict__ Qg,
    short* __restrict__ Kg, short* __restrict__ Vtg) {
  __shared__ __align__(16) short As[128][64];  // 16 KB
  __shared__ __align__(16) short Bs[128][64];  // 16 KB
  const int tid = threadIdx.x, lane = tid & 63, w = tid >> 6;
  const int bid = blockIdx.x;
  const int x = bid & 7, loc = bid >> 3;          // XCD id, local 0..95
  const int bn = x * 3 + loc % 3;                 // 0..23
  const int bm = loc / 3;                         // 0..31
  const int wm = w >> 1, wn = w & 1;              // wave tile 64 x 64
  const int c0 = lane & 15, g = lane >> 4;
  const int lr8 = lane >> 3;                      // row within 8-row chunk
  const int ls8 = (lane & 7) ^ lr8;               // inverse-swizzled source slot
  const int K = 1024;
  fx4 acc[4][4] = {};

  for (int kt = 0; kt < K; kt += 64) {
#pragma unroll
    for (int i = 0; i < 4; ++i) {
      int r = w * 32 + i * 8;
      gl_lds16(&A[(size_t)(bm * 128 + r + lr8) * K + kt + ls8 * 8], &As[r][0]);
      gl_lds16(&Bt[(size_t)(bn * 128 + r + lr8) * K + kt + ls8 * 8], &Bs[r][0]);
    }
    __syncthreads();  // drains vmcnt(0): covered by the other 2 blocks (m114)
#pragma unroll
    for (int kk = 0; kk < 2; ++kk) {
      sx8 af[4], bfr[4];
      int sb = kk * 4 + g;
#pragma unroll
      for (int m = 0; m < 4; ++m) {
        int row = wm * 64 + m * 16 + c0;
        af[m] = *(const sx8*)&As[row][(sb ^ (row & 7)) * 8];
      }
#pragma unroll
      for (int n = 0; n < 4; ++n) {
        int row = wn * 64 + n * 16 + c0;
        bfr[n] = *(const sx8*)&Bs[row][(sb ^ (row & 7)) * 8];
      }
#pragma unroll
      for (int m = 0; m < 4; ++m)
#pragma unroll
        for (int n = 0; n < 4; ++n) acc[m][n] = mfma16(af[m], bfr[n], acc[m][n]);
    }
    __syncthreads();
  }

  // scatter epilogue (C/D frag layout: row = g*4 + r, col = c0)
  const float SCALE_Q = 0.125f * 1.4426950408889634f;  // fold 1/sqrt(64)*log2e
#pragma unroll
  for (int m = 0; m < 4; ++m) {
#pragma unroll
    for (int n = 0; n < 4; ++n) {
      int col = bn * 128 + wn * 64 + n * 16 + c0;
      int row0 = bm * 128 + wm * 64 + m * 16 + g * 4;
      float bv = bias[col];
      int b = row0 >> 10, s0 = row0 & 1023;
      if (col < 1024) {
        int h = col >> 6, d = col & 63;
        size_t base = ((size_t)(b * 16 + h) * 1024) * 64 + d;
#pragma unroll
        for (int r = 0; r < 4; ++r)
          Qg[base + (size_t)(s0 + r) * 64] = f2bf((acc[m][n][r] + bv) * SCALE_Q);
      } else if (col < 2048) {
        int c = col - 1024, h = c >> 6, d = c & 63;
        size_t base = ((size_t)(b * 16 + h) * 1024) * 64 + d;
#pragma unroll
        for (int r = 0; r < 4; ++r)
          Kg[base + (size_t)(s0 + r) * 64] = f2bf(acc[m][n][r] + bv);
      } else {
        int c = col - 2048, h = c >> 6, d = c & 63;
        sx4 v;
#pragma unroll
        for (int r = 0; r < 4; ++r) v[r] = f2bf(acc[m][n][r] + bv);
        *(sx4*)&Vtg[((size_t)(b * 16 + h) * 64 + d) * 1024 + s0] = v;
      }
    }
  }
}

// ---------------- proj GEMM: 128^2 tile, T3-minimum loop (R18) --------------
__global__ __launch_bounds__(512, 4) void gemm_proj(
    const short* __restrict__ A, const short* __restrict__ Bt,
    const float* __restrict__ bias, const float* __restrict__ aw,
    const float* __restrict__ ab, float* __restrict__ Out) {
  __shared__ __align__(16) short As[2][128][64];  // 32 KB
  __shared__ __align__(16) short Bs[2][128][64];  // 32 KB
  const int tid = threadIdx.x, lane = tid & 63, w = tid >> 6;
  const int bid = blockIdx.x;
  const int x = bid & 7, k = bid >> 3;
  const int bn = x, bm = k;  // nbn=8: one bn column per XCD
  const int wm = w >> 2, wn = w & 3;
  const int c0 = lane & 15, g = lane >> 4;
  const int lr8 = lane >> 3, ls8 = (lane & 7) ^ lr8;
  const int K = 1024, N = 1024;
  fx4 acc[4][2] = {};

  auto STAGE = [&](int bf, int kt) {
#pragma unroll
    for (int i = 0; i < 2; ++i) {
      int idx = w * 2 + i;
      gl_lds16(&A[(size_t)(bm * 128 + idx * 8 + lr8) * K + kt + ls8 * 8],
               &As[bf][idx * 8][0]);
      gl_lds16(&Bt[(size_t)(bn * 128 + idx * 8 + lr8) * K + kt + ls8 * 8],
               &Bs[bf][idx * 8][0]);
    }
  };

  STAGE(0, 0);
  VMCNT0;
  BARRIER;
  for (int t = 0; t < 16; ++t) {
    const int bf = t & 1;
    if (t + 1 < 16) STAGE(bf ^ 1, (t + 1) * 64);
#pragma unroll
    for (int kk = 0; kk < 2; ++kk) {
      sx8 af[4], bfr[2];
      int sb = kk * 4 + g;
#pragma unroll
      for (int m = 0; m < 4; ++m) {
        int row = wm * 64 + m * 16 + c0;
        af[m] = *(const sx8*)&As[bf][row][(sb ^ (row & 7)) * 8];
      }
#pragma unroll
      for (int n = 0; n < 2; ++n) {
        int row = wn * 32 + n * 16 + c0;
        bfr[n] = *(const sx8*)&Bs[bf][row][(sb ^ (row & 7)) * 8];
      }
#pragma unroll
      for (int m = 0; m < 4; ++m)
#pragma unroll
        for (int n = 0; n < 2; ++n) acc[m][n] = mfma16(af[m], bfr[n], acc[m][n]);
    }
    if (t + 1 < 16) {
      VMCNT0;
      BARRIER;
    }
  }

#pragma unroll
  for (int m = 0; m < 4; ++m) {
#pragma unroll
    for (int n = 0; n < 2; ++n) {
      int col = bn * 128 + wn * 32 + n * 16 + c0;
      int row0 = bm * 128 + wm * 64 + m * 16 + g * 4;
      float bv = bias[col], wv = aw[col], av = ab[col];
#pragma unroll
      for (int r = 0; r < 4; ++r)
        Out[(size_t)(row0 + r) * N + col] = (acc[m][n][r] + bv) * wv + av;
    }
  }
}

// ---------------- flash attention (causal), T3-minimum loop (R18) -----------
__global__ __launch_bounds__(256, 4) void attn_kernel(const short* __restrict__ Qg,
                                                      const short* __restrict__ Kg,
                                                      const short* __restrict__ Vtg,
                                                      short* __restrict__ AO) {
  __shared__ __align__(16) short Ks[2][64][64];   // 16 KB
  __shared__ __align__(16) short Vts[2][64][64];  // 16 KB
  __shared__ __align__(16) short Ps[4][16 * 64];  // 8 KB (per-wave private)
  const int tid = threadIdx.x, lane = tid & 63, w = tid >> 6;
  const int bid = blockIdx.x;
  const int u = bid >> 8, v = bid & 255, bh = v >> 2, jj = v & 3;
  const int qt = (u == 0) ? jj : (u == 1) ? 7 - jj : (u == 2) ? 8 + jj : 15 - jj;
  const int b = bh >> 4, h = bh & 15;
  const int c0 = lane & 15, g = lane >> 4;
  const int lr8 = lane >> 3, ls8 = (lane & 7) ^ lr8;
  const int q0 = qt * 64 + w * 16;
  const short* Qp = Qg + (size_t)bh * 65536;
  const short* Kp = Kg + (size_t)bh * 65536;
  const short* Vp = Vtg + (size_t)bh * 65536;
  short* pbase = &Ps[w][0];
  const int s8 = (c0 & 7) * 8;  // P swizzle

  sx8 qf[2];
#pragma unroll
  for (int kk = 0; kk < 2; ++kk)
    qf[kk] = *(const sx8*)&Qp[(size_t)(q0 + c0) * 64 + kk * 32 + g * 8];

  fx4 o[4] = {};
  float mrun = -1e30f, lrun = 0.f;
  const int q_glob = q0 + c0;

  auto STAGE = [&](int bf, int kv0) {
#pragma unroll
    for (int i = 0; i < 2; ++i) {
      int idx = w * 2 + i;
      gl_lds16(&Kp[(size_t)(kv0 + idx * 8 + lr8) * 64 + ls8 * 8], &Ks[bf][idx * 8][0]);
    }
#pragma unroll
    for (int i = 0; i < 2; ++i) {
      int idx = w * 2 + i;
      gl_lds16(&Vp[(size_t)(idx * 8 + lr8) * 1024 + kv0 + ls8 * 8], &Vts[bf][idx * 8][0]);
    }
  };

  STAGE(0, 0);
  VMCNT0;
  BARRIER;
  for (int t = 0; t <= qt; ++t) {
    const int kv0 = t * 64;
    const int bf = t & 1;
    const bool more = t < qt;
    if (more) STAGE(bf ^ 1, kv0 + 64);  // issue BEFORE compute

    fx4 st[4];
    __builtin_amdgcn_s_setprio(1);
#pragma unroll
    for (int mf = 0; mf < 4; ++mf) {
      int row = mf * 16 + c0;
      sx8 kf0 = *(const sx8*)&Ks[bf][row][(g ^ (row & 7)) * 8];
      sx8 kf1 = *(const sx8*)&Ks[bf][row][((4 + g) ^ (row & 7)) * 8];
      fx4 z = {0.f, 0.f, 0.f, 0.f};
      z = mfma16(kf0, qf[0], z);
      st[mf] = mfma16(kf1, qf[1], z);
    }
    __builtin_amdgcn_s_setprio(0);

    float pmax = -1e30f;
    if (t == qt) {
#pragma unroll
      for (int mf = 0; mf < 4; ++mf)
#pragma unroll
        for (int r = 0; r < 4; ++r) {
          int kv = kv0 + mf * 16 + g * 4 + r;
          float z = (kv > q_glob) ? -1e30f : st[mf][r];
          st[mf][r] = z;
          pmax = fmaxf(pmax, z);
        }
    } else {
#pragma unroll
      for (int mf = 0; mf < 4; ++mf)
#pragma unroll
        for (int r = 0; r < 4; ++r) pmax = fmaxf(pmax, st[mf][r]);
    }
    pmax = fmaxf(pmax, __shfl_xor(pmax, 16));
    pmax = fmaxf(pmax, __shfl_xor(pmax, 32));
    float mnew = fmaxf(mrun, pmax);
    float alpha = __builtin_amdgcn_exp2f(mrun - mnew);
    float psum = 0.f;
#pragma unroll
    for (int mf = 0; mf < 4; ++mf) {
      sx4 pv;
#pragma unroll
      for (int r = 0; r < 4; ++r) {
        float pp = __builtin_amdgcn_exp2f(st[mf][r] - mnew);
        psum += pp;
        pv[r] = f2bf(pp);
      }
      *(sx4*)&pbase[c0 * 64 + ((mf * 16 + g * 4) ^ s8)] = pv;
    }
    psum += __shfl_xor(psum, 16);
    psum += __shfl_xor(psum, 32);
    lrun = lrun * alpha + psum;
    mrun = mnew;
#pragma unroll
    for (int mf = 0; mf < 4; ++mf) o[mf] *= alpha;

    __builtin_amdgcn_s_setprio(1);
#pragma unroll
    for (int kk = 0; kk < 2; ++kk) {
      sx8 pbf = *(const sx8*)&pbase[c0 * 64 + ((kk * 32 + g * 8) ^ s8)];
#pragma unroll
      for (int mf = 0; mf < 4; ++mf) {
        int row = mf * 16 + c0;
        sx8 vaf = *(const sx8*)&Vts[bf][row][((kk * 4 + g) ^ (row & 7)) * 8];
        o[mf] = mfma16(vaf, pbf, o[mf]);
      }
    }
    __builtin_amdgcn_s_setprio(0);

    if (more) {
      VMCNT0;
      BARRIER;
    }
  }

  float inv = 1.0f / lrun;
  int q = q0 + c0;
#pragma unroll
  for (int mf = 0; mf < 4; ++mf) {
    sx4 v4;
#pragma unroll
    for (int r = 0; r < 4; ++r) v4[r] = f2bf(o[mf][r] * inv);
    int d0 = mf * 16 + g * 4;
    *(sx4*)&AO[((size_t)(b * 1024 + q)) * 1024 + h * 64 + d0] = v4;
  }
}

// ---------------- launch ----------------------------------------------------
extern "C" void kernel_launch(void* const* d_in, const int* in_sizes, int n_in,
                              void* d_out, int out_size, void* d_ws, size_t ws_size,
                              hipStream_t stream) {
  const float* hs  = (const float*)d_in[0];
  const float* caw = (const float*)d_in[1];
  const float* cab = (const float*)d_in[2];
  const float* cpw = (const float*)d_in[3];
  const float* cpb = (const float*)d_in[4];
  const float* afw = (const float*)d_in[5];
  const float* afb = (const float*)d_in[6];
  float* out = (float*)d_out;
  char* ws = (char*)d_ws;

  short* hsb    = (short*)(ws);                       // [4096][1024] bf16
  short* ao     = (short*)(ws);                       // overlaps hsb
  short* wqkvt  = (short*)(ws + ((size_t)8  << 20));  // [3072][1024] bf16
  short* wprojt = (short*)(ws + ((size_t)14 << 20));  // [1024][1024] bf16
  short* Qg     = (short*)(ws + ((size_t)16 << 20));  // [4][16][1024][64]
  short* Kg     = (short*)(ws + ((size_t)24 << 20));  // [4][16][1024][64]
  short* Vtg    = (short*)(ws + ((size_t)32 << 20));  // [4][16][64][1024]

  prologue<<<8192, 256, 0, stream>>>(hs, hsb, caw, wqkvt, cpw, wprojt);
  gemm_qkv<<<768, 256, 0, stream>>>(hsb, wqkvt, cab, Qg, Kg, Vtg);
  attn_kernel<<<1024, 256, 0, stream>>>(Qg, Kg, Vtg, ao);
  gemm_proj<<<256, 512, 0, stream>>>(ao, wprojt, cpb, afw, afb, out);
}

// Round 20
// 92.096 us; speedup vs baseline: 1.0897x; 1.0897x over previous
//
#include <hip/hip_runtime.h>

// AffineGPT2Attention: B=4, S=1024, D=1024, H=16, Dh=64
// R20 = R18-exact restore (best measured: 92.7us). R19's m97-clone regressed
// (unsatisfiable launch_bounds(256,8) at 112 VGPR -> occupancy 15.8%).
// QKV BM128/BN256/BK32 grid 384, T3-min loop (best of 13 variants: 46-48us =
// ~550TF, at the guide's measured 2-phase structure ceiling for this shape).
// Fused prologue; attn 64-q T3-min; proj 128^2 T3-min.

typedef __attribute__((ext_vector_type(4))) float  fx4;
typedef __attribute__((ext_vector_type(4))) short  sx4;
typedef __attribute__((ext_vector_type(8))) short  sx8;
typedef __attribute__((ext_vector_type(4))) float  f32x4;
typedef __attribute__((ext_vector_type(8))) __bf16 bf16x8;

#define DEVI static __device__ __forceinline__
#define BARRIER asm volatile("s_barrier" ::: "memory")
#define VMCNT0  asm volatile("s_waitcnt vmcnt(0)" ::: "memory")

DEVI short f2bf(float f) {  // f32 -> bf16 (RNE)
  unsigned u = __builtin_bit_cast(unsigned, f);
  u = (u + 0x7FFFu + ((u >> 16) & 1u)) >> 16;
  return (short)u;
}

DEVI fx4 mfma16(sx8 a, sx8 b, fx4 c) {
  return __builtin_amdgcn_mfma_f32_16x16x32_bf16(
      __builtin_bit_cast(bf16x8, a), __builtin_bit_cast(bf16x8, b), c, 0, 0, 0);
}

DEVI void gl_lds16(const void* g, void* l) {  // async global->LDS, 16B/lane
  __builtin_amdgcn_global_load_lds(
      (const __attribute__((address_space(1))) void*)g,
      (__attribute__((address_space(3))) void*)l, 16, 0, 0);
}

// ---------------- fused prologue: weight transposes + hs cast ---------------
// bid <  3072 : caw [1024][3072] -> wqkvt [3072][1024] bf16 (32x32 tiles)
// bid <  4096 : cpw [1024][1024] -> wprojt [1024][1024] bf16
// bid >= 4096 : hs f32 -> hsb bf16 (4 elems/thread, 4096 blocks)
__global__ __launch_bounds__(256) void prologue(
    const float* __restrict__ hs, short* __restrict__ hsb,
    const float* __restrict__ caw, short* __restrict__ wqkvt,
    const float* __restrict__ cpw, short* __restrict__ wprojt) {
  __shared__ float tbuf[32][33];
  const int bid = blockIdx.x, tid = threadIdx.x;
  if (bid < 4096) {
    const float* in;
    short* out;
    int C, bx, by;
    if (bid < 3072) {
      in = caw; out = wqkvt; C = 3072; bx = bid % 96; by = bid / 96;
    } else {
      int t = bid - 3072;
      in = cpw; out = wprojt; C = 1024; bx = t & 31; by = t >> 5;
    }
    const int R = 1024;
    int tx = tid & 31, ty = tid >> 5;
    int r0 = by * 32, c0 = bx * 32;
#pragma unroll
    for (int i = 0; i < 4; ++i)
      tbuf[ty + i * 8][tx] = in[(size_t)(r0 + ty + i * 8) * C + c0 + tx];
    __syncthreads();
#pragma unroll
    for (int i = 0; i < 4; ++i)
      out[(size_t)(c0 + ty + i * 8) * R + r0 + tx] = f2bf(tbuf[tx][ty + i * 8]);
  } else {
    int i = (bid - 4096) * 256 + tid;
    f32x4 v = *(const f32x4*)&hs[(size_t)i * 4];
    sx4 o;
#pragma unroll
    for (int j = 0; j < 4; ++j) o[j] = f2bf(v[j]);
    *(sx4*)&hsb[(size_t)i * 4] = o;
  }
}

// ---------------- QKV GEMM: BM=128, BN=256, BK=32, grid 384 (R15/R18) -------
// T3-minimum loop: STAGE(t+1) ; reads+MFMA(t) ; vmcnt(0) ; barrier.
// Packed LDS (row-pair -> 64B row) keeps 0-conflict swizzle (verified R14).
__global__ __launch_bounds__(512, 4) void gemm_qkv(
    const short* __restrict__ A, const short* __restrict__ Bt,
    const float* __restrict__ bias, short* __restrict__ Qg,
    short* __restrict__ Kg, short* __restrict__ Vtg) {
  __shared__ __align__(16) short As[2][64][64];   // 16 KB (128 logical rows)
  __shared__ __align__(16) short Bs[2][128][64];  // 32 KB (256 logical rows)
  const int tid = threadIdx.x, lane = tid & 63, w = tid >> 6;
  const int bid = blockIdx.x;
  const int x = bid & 7, loc = bid >> 3;          // XCD id, local 0..47
  const int bn = (x & 3) * 3 + loc % 3;           // 0..11
  const int bm = (x >> 2) * 16 + loc / 3;         // 0..31
  const int wm = w >> 2, wn = w & 3;              // wave tile 64 x 64
  const int c0 = lane & 15, g = lane >> 4;
  const int l3 = lane >> 3, l7 = lane & 7;
  const int slog = l7 ^ l3;                       // logical slot this lane stages
  const int par = slog >> 2, gg = slog & 3;       // row parity, k-group
  const int K = 1024;
  fx4 acc[4][4] = {};

  auto STAGE = [&](int bf, int kt) {  // 3 gl_lds per thread (1 A + 2 B)
    {
      int row = w * 16 + l3 * 2 + par;            // A logical row 0..127
      gl_lds16(&A[(size_t)(bm * 128 + row) * K + kt + gg * 8], &As[bf][w * 8][0]);
    }
#pragma unroll
    for (int i = 0; i < 2; ++i) {
      int ch = w * 2 + i;                         // B chunk 0..15
      int row = ch * 16 + l3 * 2 + par;           // B logical row 0..255
      gl_lds16(&Bt[(size_t)(bn * 256 + row) * K + kt + gg * 8], &Bs[bf][ch * 8][0]);
    }
  };

  STAGE(0, 0);
  VMCNT0;
  BARRIER;
  for (int t = 0; t < 32; ++t) {
    const int bf = t & 1;
    if (t + 1 < 32) STAGE(bf ^ 1, (t + 1) * 32);  // issue BEFORE compute

    sx8 af[4], bfr[4];
#pragma unroll
    for (int m = 0; m < 4; ++m) {
      int r = wm * 64 + m * 16 + c0, pr = r >> 1;
      int sl = (((r & 1) << 2) | g) ^ (pr & 7);
      af[m] = *(const sx8*)&As[bf][pr][sl * 8];
    }
#pragma unroll
    for (int n = 0; n < 4; ++n) {
      int r = wn * 64 + n * 16 + c0, pr = r >> 1;
      int sl = (((r & 1) << 2) | g) ^ (pr & 7);
      bfr[n] = *(const sx8*)&Bs[bf][pr][sl * 8];
    }
    __builtin_amdgcn_s_setprio(1);
#pragma unroll
    for (int m = 0; m < 4; ++m)
#pragma unroll
      for (int n = 0; n < 4; ++n) acc[m][n] = mfma16(af[m], bfr[n], acc[m][n]);
    __builtin_amdgcn_s_setprio(0);

    if (t + 1 < 32) {
      VMCNT0;   // t+1's DMA issued before compute -> mostly landed
      BARRIER;  // single barrier: visibility + WAR protection
    }
  }

  // scatter epilogue (C/D frag layout: row = g*4 + r, col = c0)
  const float SCALE_Q = 0.125f * 1.4426950408889634f;  // fold 1/sqrt(64)*log2e
#pragma unroll
  for (int m = 0; m < 4; ++m) {
#pragma unroll
    for (int n = 0; n < 4; ++n) {
      int col = bn * 256 + wn * 64 + n * 16 + c0;
      int row0 = bm * 128 + wm * 64 + m * 16 + g * 4;
      float bv = bias[col];
      int b = row0 >> 10, s0 = row0 & 1023;
      if (col < 1024) {
        int h = col >> 6, d = col & 63;
        size_t base = ((size_t)(b * 16 + h) * 1024) * 64 + d;
#pragma unroll
        for (int r = 0; r < 4; ++r)
          Qg[base + (size_t)(s0 + r) * 64] = f2bf((acc[m][n][r] + bv) * SCALE_Q);
      } else if (col < 2048) {
        int c = col - 1024, h = c >> 6, d = c & 63;
        size_t base = ((size_t)(b * 16 + h) * 1024) * 64 + d;
#pragma unroll
        for (int r = 0; r < 4; ++r)
          Kg[base + (size_t)(s0 + r) * 64] = f2bf(acc[m][n][r] + bv);
      } else {
        int c = col - 2048, h = c >> 6, d = c & 63;
        sx4 v;
#pragma unroll
        for (int r = 0; r < 4; ++r) v[r] = f2bf(acc[m][n][r] + bv);
        *(sx4*)&Vtg[((size_t)(b * 16 + h) * 64 + d) * 1024 + s0] = v;
      }
    }
  }
}

// ---------------- proj GEMM: 128^2 tile, T3-minimum loop --------------------
__global__ __launch_bounds__(512, 4) void gemm_proj(
    const short* __restrict__ A, const short* __restrict__ Bt,
    const float* __restrict__ bias, const float* __restrict__ aw,
    const float* __restrict__ ab, float* __restrict__ Out) {
  __shared__ __align__(16) short As[2][128][64];  // 32 KB
  __shared__ __align__(16) short Bs[2][128][64];  // 32 KB
  const int tid = threadIdx.x, lane = tid & 63, w = tid >> 6;
  const int bid = blockIdx.x;
  const int x = bid & 7, k = bid >> 3;
  const int bn = x, bm = k;  // nbn=8: one bn column per XCD
  const int wm = w >> 2, wn = w & 3;
  const int c0 = lane & 15, g = lane >> 4;
  const int lr8 = lane >> 3, ls8 = (lane & 7) ^ lr8;
  const int K = 1024, N = 1024;
  fx4 acc[4][2] = {};

  auto STAGE = [&](int bf, int kt) {
#pragma unroll
    for (int i = 0; i < 2; ++i) {
      int idx = w * 2 + i;
      gl_lds16(&A[(size_t)(bm * 128 + idx * 8 + lr8) * K + kt + ls8 * 8],
               &As[bf][idx * 8][0]);
      gl_lds16(&Bt[(size_t)(bn * 128 + idx * 8 + lr8) * K + kt + ls8 * 8],
               &Bs[bf][idx * 8][0]);
    }
  };

  STAGE(0, 0);
  VMCNT0;
  BARRIER;
  for (int t = 0; t < 16; ++t) {
    const int bf = t & 1;
    if (t + 1 < 16) STAGE(bf ^ 1, (t + 1) * 64);
#pragma unroll
    for (int kk = 0; kk < 2; ++kk) {
      sx8 af[4], bfr[2];
      int sb = kk * 4 + g;
#pragma unroll
      for (int m = 0; m < 4; ++m) {
        int row = wm * 64 + m * 16 + c0;
        af[m] = *(const sx8*)&As[bf][row][(sb ^ (row & 7)) * 8];
      }
#pragma unroll
      for (int n = 0; n < 2; ++n) {
        int row = wn * 32 + n * 16 + c0;
        bfr[n] = *(const sx8*)&Bs[bf][row][(sb ^ (row & 7)) * 8];
      }
#pragma unroll
      for (int m = 0; m < 4; ++m)
#pragma unroll
        for (int n = 0; n < 2; ++n) acc[m][n] = mfma16(af[m], bfr[n], acc[m][n]);
    }
    if (t + 1 < 16) {
      VMCNT0;
      BARRIER;
    }
  }

#pragma unroll
  for (int m = 0; m < 4; ++m) {
#pragma unroll
    for (int n = 0; n < 2; ++n) {
      int col = bn * 128 + wn * 32 + n * 16 + c0;
      int row0 = bm * 128 + wm * 64 + m * 16 + g * 4;
      float bv = bias[col], wv = aw[col], av = ab[col];
#pragma unroll
      for (int r = 0; r < 4; ++r)
        Out[(size_t)(row0 + r) * N + col] = (acc[m][n][r] + bv) * wv + av;
    }
  }
}

// ---------------- flash attention (causal), T3-minimum loop -----------------
__global__ __launch_bounds__(256, 4) void attn_kernel(const short* __restrict__ Qg,
                                                      const short* __restrict__ Kg,
                                                      const short* __restrict__ Vtg,
                                                      short* __restrict__ AO) {
  __shared__ __align__(16) short Ks[2][64][64];   // 16 KB
  __shared__ __align__(16) short Vts[2][64][64];  // 16 KB
  __shared__ __align__(16) short Ps[4][16 * 64];  // 8 KB (per-wave private)
  const int tid = threadIdx.x, lane = tid & 63, w = tid >> 6;
  const int bid = blockIdx.x;
  const int u = bid >> 8, v = bid & 255, bh = v >> 2, jj = v & 3;
  const int qt = (u == 0) ? jj : (u == 1) ? 7 - jj : (u == 2) ? 8 + jj : 15 - jj;
  const int b = bh >> 4, h = bh & 15;
  const int c0 = lane & 15, g = lane >> 4;
  const int lr8 = lane >> 3, ls8 = (lane & 7) ^ lr8;
  const int q0 = qt * 64 + w * 16;
  const short* Qp = Qg + (size_t)bh * 65536;
  const short* Kp = Kg + (size_t)bh * 65536;
  const short* Vp = Vtg + (size_t)bh * 65536;
  short* pbase = &Ps[w][0];
  const int s8 = (c0 & 7) * 8;  // P swizzle

  sx8 qf[2];
#pragma unroll
  for (int kk = 0; kk < 2; ++kk)
    qf[kk] = *(const sx8*)&Qp[(size_t)(q0 + c0) * 64 + kk * 32 + g * 8];

  fx4 o[4] = {};
  float mrun = -1e30f, lrun = 0.f;
  const int q_glob = q0 + c0;

  auto STAGE = [&](int bf, int kv0) {
#pragma unroll
    for (int i = 0; i < 2; ++i) {
      int idx = w * 2 + i;
      gl_lds16(&Kp[(size_t)(kv0 + idx * 8 + lr8) * 64 + ls8 * 8], &Ks[bf][idx * 8][0]);
    }
#pragma unroll
    for (int i = 0; i < 2; ++i) {
      int idx = w * 2 + i;
      gl_lds16(&Vp[(size_t)(idx * 8 + lr8) * 1024 + kv0 + ls8 * 8], &Vts[bf][idx * 8][0]);
    }
  };

  STAGE(0, 0);
  VMCNT0;
  BARRIER;
  for (int t = 0; t <= qt; ++t) {
    const int kv0 = t * 64;
    const int bf = t & 1;
    const bool more = t < qt;
    if (more) STAGE(bf ^ 1, kv0 + 64);  // issue BEFORE compute

    fx4 st[4];
    __builtin_amdgcn_s_setprio(1);
#pragma unroll
    for (int mf = 0; mf < 4; ++mf) {
      int row = mf * 16 + c0;
      sx8 kf0 = *(const sx8*)&Ks[bf][row][(g ^ (row & 7)) * 8];
      sx8 kf1 = *(const sx8*)&Ks[bf][row][((4 + g) ^ (row & 7)) * 8];
      fx4 z = {0.f, 0.f, 0.f, 0.f};
      z = mfma16(kf0, qf[0], z);
      st[mf] = mfma16(kf1, qf[1], z);
    }
    __builtin_amdgcn_s_setprio(0);

    float pmax = -1e30f;
    if (t == qt) {
#pragma unroll
      for (int mf = 0; mf < 4; ++mf)
#pragma unroll
        for (int r = 0; r < 4; ++r) {
          int kv = kv0 + mf * 16 + g * 4 + r;
          float z = (kv > q_glob) ? -1e30f : st[mf][r];
          st[mf][r] = z;
          pmax = fmaxf(pmax, z);
        }
    } else {
#pragma unroll
      for (int mf = 0; mf < 4; ++mf)
#pragma unroll
        for (int r = 0; r < 4; ++r) pmax = fmaxf(pmax, st[mf][r]);
    }
    pmax = fmaxf(pmax, __shfl_xor(pmax, 16));
    pmax = fmaxf(pmax, __shfl_xor(pmax, 32));
    float mnew = fmaxf(mrun, pmax);
    float alpha = __builtin_amdgcn_exp2f(mrun - mnew);
    float psum = 0.f;
#pragma unroll
    for (int mf = 0; mf < 4; ++mf) {
      sx4 pv;
#pragma unroll
      for (int r = 0; r < 4; ++r) {
        float pp = __builtin_amdgcn_exp2f(st[mf][r] - mnew);
        psum += pp;
        pv[r] = f2bf(pp);
      }
      *(sx4*)&pbase[c0 * 64 + ((mf * 16 + g * 4) ^ s8)] = pv;
    }
    psum += __shfl_xor(psum, 16);
    psum += __shfl_xor(psum, 32);
    lrun = lrun * alpha + psum;
    mrun = mnew;
#pragma unroll
    for (int mf = 0; mf < 4; ++mf) o[mf] *= alpha;

    __builtin_amdgcn_s_setprio(1);
#pragma unroll
    for (int kk = 0; kk < 2; ++kk) {
      sx8 pbf = *(const sx8*)&pbase[c0 * 64 + ((kk * 32 + g * 8) ^ s8)];
#pragma unroll
      for (int mf = 0; mf < 4; ++mf) {
        int row = mf * 16 + c0;
        sx8 vaf = *(const sx8*)&Vts[bf][row][((kk * 4 + g) ^ (row & 7)) * 8];
        o[mf] = mfma16(vaf, pbf, o[mf]);
      }
    }
    __builtin_amdgcn_s_setprio(0);

    if (more) {
      VMCNT0;
      BARRIER;
    }
  }

  float inv = 1.0f / lrun;
  int q = q0 + c0;
#pragma unroll
  for (int mf = 0; mf < 4; ++mf) {
    sx4 v4;
#pragma unroll
    for (int r = 0; r < 4; ++r) v4[r] = f2bf(o[mf][r] * inv);
    int d0 = mf * 16 + g * 4;
    *(sx4*)&AO[((size_t)(b * 1024 + q)) * 1024 + h * 64 + d0] = v4;
  }
}

// ---------------- launch ----------------------------------------------------
extern "C" void kernel_launch(void* const* d_in, const int* in_sizes, int n_in,
                              void* d_out, int out_size, void* d_ws, size_t ws_size,
                              hipStream_t stream) {
  const float* hs  = (const float*)d_in[0];
  const float* caw = (const float*)d_in[1];
  const float* cab = (const float*)d_in[2];
  const float* cpw = (const float*)d_in[3];
  const float* cpb = (const float*)d_in[4];
  const float* afw = (const float*)d_in[5];
  const float* afb = (const float*)d_in[6];
  float* out = (float*)d_out;
  char* ws = (char*)d_ws;

  short* hsb    = (short*)(ws);                       // [4096][1024] bf16
  short* ao     = (short*)(ws);                       // overlaps hsb
  short* wqkvt  = (short*)(ws + ((size_t)8  << 20));  // [3072][1024] bf16
  short* wprojt = (short*)(ws + ((size_t)14 << 20));  // [1024][1024] bf16
  short* Qg     = (short*)(ws + ((size_t)16 << 20));  // [4][16][1024][64]
  short* Kg     = (short*)(ws + ((size_t)24 << 20));  // [4][16][1024][64]
  short* Vtg    = (short*)(ws + ((size_t)32 << 20));  // [4][16][64][1024]

  prologue<<<8192, 256, 0, stream>>>(hs, hsb, caw, wqkvt, cpw, wprojt);
  gemm_qkv<<<384, 512, 0, stream>>>(hsb, wqkvt, cab, Qg, Kg, Vtg);
  attn_kernel<<<1024, 256, 0, stream>>>(Qg, Kg, Vtg, ao);
  gemm_proj<<<256, 512, 0, stream>>>(ao, wprojt, cpb, afw, afb, out);
}